// Round 11
// baseline (966.353 us; speedup 1.0000x reference)
//
#include <hip/hip_runtime.h>
#include <hip/hip_cooperative_groups.h>
#include <hip/hip_bf16.h>
#include <hip/hip_fp16.h>

namespace cg = cooperative_groups;

// Inputs/outputs are FP32 (verified R3/R6).
// R10: KV-in-regs OR weights-in-regs — never both (compiler demotes silently).
// R11: redundant all-wave broadcast stages LOSE. R12: dot2+fp16 LDS; latency-bound.
// R13: wall time = per-step critical path. R14: mega-wave0 + 2 barriers -> 236us;
//   chip runs ~1.1GHz at this occupancy (DVFS).
// R15: weights-in-VGPR regressed. R16: launch gap ~10-20us/kernel.
// R17: encoder 3-way fusion regressed; k_dec cross-o-proj partials won.
// R18: attn 2-way split -> issue-bound; k_dec noise band 230-240us.
// R19 lesson: encoder bodies model to ~160us@1.1GHz but encoder+gaps measure 337us
//   -> ~150us is inter-kernel serialization. Launch COUNT is the lever.
// R20: whole encoder as ONE cooperative kernel (768 blocks, 5 phases, grid.sync()
//   between; weights staged once per block not per tile). Fallback to separate
//   launches if cooperative launch is rejected. k_dec unchanged.

constexpr int kB  = 128;
constexpr int kS  = 512;
constexpr int kT  = 64;
constexpr int kD  = 48;
constexpr int kFF = 128;
constexpr int kNH = 4;
constexpr int kHD = 12;

__device__ __forceinline__ void wsync(){
  __builtin_amdgcn_wave_barrier();
  asm volatile("" ::: "memory");
}

// ---- DPP wave64 reductions (VALU-speed) ----
template<int CTRL,int RM,int BM,bool BC>
__device__ __forceinline__ float dppmov(float x, float old){
  return __builtin_bit_cast(float, __builtin_amdgcn_update_dpp(
      __builtin_bit_cast(int, old), __builtin_bit_cast(int, x), CTRL, RM, BM, BC));
}
// sum across 64 lanes, result uniform in all lanes
__device__ __forceinline__ float wsum(float x){
  x += dppmov<0x111,0xf,0xf,true>(x, 0.f);   // row_shr:1
  x += dppmov<0x112,0xf,0xf,true>(x, 0.f);   // row_shr:2
  x += dppmov<0x114,0xf,0xf,true>(x, 0.f);   // row_shr:4
  x += dppmov<0x118,0xf,0xf,true>(x, 0.f);   // row_shr:8
  x += dppmov<0x142,0xa,0xf,true>(x, 0.f);   // row_bcast:15 -> rows 1,3
  x += dppmov<0x143,0xc,0xf,true>(x, 0.f);   // row_bcast:31 -> rows 2,3
  return __builtin_bit_cast(float, __builtin_amdgcn_readlane(__builtin_bit_cast(int, x), 63));
}
// sum within each 16-lane row; result valid at lane 15 of each row
__device__ __forceinline__ float rowsum16(float x){
  x += dppmov<0x111,0xf,0xf,true>(x, 0.f);
  x += dppmov<0x112,0xf,0xf,true>(x, 0.f);
  x += dppmov<0x114,0xf,0xf,true>(x, 0.f);
  x += dppmov<0x118,0xf,0xf,true>(x, 0.f);
  return x;
}

// pe[p, 2i] = sin(p * exp(-2i*ln(10000)/48)), pe[p, 2i+1] = cos(...)
__device__ __forceinline__ float pe_val(int p, int j){   // precise (table init)
  int i = j >> 1;
  float f = expf(-0.19188209108283716f * (float)(2*i));
  float a = (float)p * f;
  return (j & 1) ? cosf(a) : sinf(a);
}
__device__ __forceinline__ float pe_fast(int p, int j){  // encoder embed
  int i = j >> 1;
  float f = __expf(-0.19188209108283716f * (float)(2*i));
  float a = (float)p * f;
  return (j & 1) ? __cosf(a) : __sinf(a);
}

// ---- packed fp16 dot: d = a.x*b.x + a.y*b.y + c (v_dot2_f32_f16) ----
typedef _Float16 h2v __attribute__((ext_vector_type(2)));
union H2U { __half2 h; h2v v; };
__device__ __forceinline__ float fdot2(__half2 a, __half2 b, float c){
#if __has_builtin(__builtin_amdgcn_fdot2)
  H2U ua, ub; ua.h=a; ub.h=b;
  return __builtin_amdgcn_fdot2(ua.v, ub.v, c, false);
#else
  float2 fa=__half22float2(a), fb=__half22float2(b);
  return fmaf(fa.y, fb.y, fmaf(fa.x, fb.x, c));
#endif
}
union F4H2 { float4 f; __half2 h[4]; };

// 48-dot, x (LDS or reg array) vs w (LDS), 4 accumulator chains
__device__ __forceinline__ float dot48d(const __half2* x, const __half* w){
  const __half2* w2=(const __half2*)w;
  float a0=0.f,a1=0.f,a2=0.f,a3=0.f;
  #pragma unroll
  for(int c=0;c<6;c++){
    a0=fdot2(x[4*c+0],w2[4*c+0],a0);
    a1=fdot2(x[4*c+1],w2[4*c+1],a1);
    a2=fdot2(x[4*c+2],w2[4*c+2],a2);
    a3=fdot2(x[4*c+3],w2[4*c+3],a3);
  }
  return (a0+a1)+(a2+a3);
}
// 128-dot, 8 accumulator chains
__device__ __forceinline__ float dot128d(const __half2* x, const __half* w){
  const __half2* w2=(const __half2*)w;
  float a0=0.f,a1=0.f,a2=0.f,a3=0.f,a4=0.f,a5=0.f,a6=0.f,a7=0.f;
  #pragma unroll
  for(int c=0;c<8;c++){
    a0=fdot2(x[8*c+0],w2[8*c+0],a0);
    a1=fdot2(x[8*c+1],w2[8*c+1],a1);
    a2=fdot2(x[8*c+2],w2[8*c+2],a2);
    a3=fdot2(x[8*c+3],w2[8*c+3],a3);
    a4=fdot2(x[8*c+4],w2[8*c+4],a4);
    a5=fdot2(x[8*c+5],w2[8*c+5],a5);
    a6=fdot2(x[8*c+6],w2[8*c+6],a6);
    a7=fdot2(x[8*c+7],w2[8*c+7],a7);
  }
  return ((a0+a1)+(a2+a3))+((a4+a5)+(a6+a7));
}

// ================= encoder phases (shared by coop kernel + fallback wrappers) =================
constexpr int kArena = 38400;   // max phase LDS (FFN: 37312 B)

struct EncP {
  const float *src,*in_w,*in_b; float* X0;
  const float *wq,*bq,*wk,*bk,*wv,*bv;
  __half *Q,*K,*V;
  const float *swq,*swk,*swv,*swo,*cwq,*cwo,*dw1,*dw2; __half* Wh;
  __half* OP; float* lP;
  const float *wo,*bo,*g1,*b1g; __half* X1;
  const float *w1,*b1,*w2,*b2,*g2,*b2g; float* Xm;
  const float *ckw,*ckb,*cvw,*cvb; __half *Kc,*Vc;
};

// ---- phase 1: embed + QKV projection (+ decoder weight prep) ----
__device__ __forceinline__ void phase_qkv(unsigned char* arena, const EncP& p){
  __half* W=(__half*)arena;                       // 16128 B
  float* bias=(float*)(arena+16128);              // 576
  __half2* xt2=(__half2*)(arena+16704);           // 3072
  int tid=threadIdx.x;
  for(int i=tid;i<3*2304;i+=256){ int m=i/2304,e=i%2304,k=e/48,j=e%48;
    const float* w=(m==0)?p.wq:((m==1)?p.wk:p.wv);
    W[m*2688+j*56+k]=__float2half(w[e]); }
  for(int i=tid;i<3*kD;i+=256){ int m=i/kD,e=i%kD;
    const float* w=(m==0)?p.bq:((m==1)?p.bk:p.bv); bias[i]=w[e]; }
  // decoder weights -> padded fp16 column-major (consumed only by k_dec)
  for(int idx=blockIdx.x*256+tid; idx<26112; idx+=gridDim.x*256){
    if(idx<13824){
      int m=idx/2304,e=idx%2304,j=e/48,k=e%48;
      const float* w=(m==0)?p.swq:((m==1)?p.swk:((m==2)?p.swv:((m==3)?p.swo:((m==4)?p.cwq:p.cwo))));
      p.Wh[m*2688+j*56+k]=__float2half(w[k*48+j]);
    } else if(idx<19968){
      int e=idx-13824,c=e/48,k=e%48;
      p.Wh[16128+c*56+k]=__float2half(p.dw1[k*128+c]);
    } else {
      int e=idx-19968,j=e/128,u=e%128;
      p.Wh[23296+j*136+u]=__float2half(p.dw2[u*48+j]);
    }
  }
  const float sc=6.928203230275509f, rs=0.28867513459481287f;
  for(long tile=blockIdx.x; tile<2048; tile+=gridDim.x){
    __syncthreads();                          // xt2 reuse + W visibility (1st iter)
    long row0=tile*32;
    for(int i=tid;i<768;i+=256){
      int r=i/24,c=i%24;
      long gr=row0+r; int s=(int)(gr&511);
      float sv=p.src[gr];
      float va=(sv*p.in_w[2*c  ]+p.in_b[2*c  ])*sc+pe_fast(s,2*c  );
      float vb=(sv*p.in_w[2*c+1]+p.in_b[2*c+1])*sc+pe_fast(s,2*c+1);
      ((float2*)p.X0)[row0*24+i]=make_float2(va,vb);
      xt2[i]=__floats2half2_rn(va,vb);
    }
    __syncthreads();
    int r=tid>>3,c0=tid&7;
    __half2 xr[24];
    #pragma unroll
    for(int u=0;u<24;u++) xr[u]=xt2[r*24+u];
    for(int c=c0;c<3*kD;c+=8){
      int m=c/kD,j=c%kD;
      float acc=bias[m*kD+j]+dot48d(xr,W+m*2688+j*56);
      if(m==0) acc*=rs;                       // fold 1/sqrt(hd) into Q
      __half* o=(m==0)?p.Q:((m==1)?p.K:p.V);
      o[(row0+r)*kD+j]=__float2half(acc);
    }
  }
}

// ---- phase 2: attention, 2-way key split; self-normalized partials ----
__device__ __forceinline__ void phase_attn(unsigned char* arena, const EncP& p){
  __half2* Ks2=(__half2*)arena;                   // 256*8*4 = 8192 B
  float*   Vs =(float*)(arena+8192);              // 12288 B
  int tid=threadIdx.x;
  const long PS=(long)kB*kNH*kS*kHD, LS=(long)kB*kNH*kS;
  for(int item=blockIdx.x; item<kB*kNH*2; item+=gridDim.x){
    __syncthreads();                          // Ks2/Vs reuse
    int part=item&1; int bh=item>>1;
    int b=bh/kNH, h=bh%kNH;
    long base=((long)b*kS)*kD + h*kHD;
    int k0=part<<8;
    for(int i=tid;i<256*6;i+=256){ int r=i/6,c=i%6;
      Ks2[r*8+c]=*(const __half2*)&p.K[base+(long)(k0+r)*kD+2*c]; }
    for(int i=tid;i<256*kHD;i+=256){ int r=i/kHD,d=i%kHD;
      Vs[i]=__half2float(p.V[base+(long)(k0+r)*kD+d]); }
    int q0=tid, q1=tid+256;
    __half2 qa2[6], qb2[6];
    {
      const __half2* qp0=(const __half2*)(p.Q+base+(long)q0*kD);
      const __half2* qp1=(const __half2*)(p.Q+base+(long)q1*kD);
      #pragma unroll
      for(int c=0;c<6;c++){ qa2[c]=qp0[c]; qb2[c]=qp1[c]; }
    }
    __syncthreads();
    float2 acc0[6], acc1[6];
    #pragma unroll
    for(int j=0;j<6;j++){ acc0[j]=make_float2(0.f,0.f); acc1[j]=make_float2(0.f,0.f); }
    float l0=0.f, l1=0.f;
    for(int k=0;k<256;k++){
      const float4* kp4=(const float4*)(Ks2+k*8);
      F4H2 u0,u1; u0.f=kp4[0]; u1.f=kp4[1];
      float sA0=0.f,sA1=0.f,sB0=0.f,sB1=0.f;
      sA0=fdot2(qa2[0],u0.h[0],sA0); sA1=fdot2(qa2[1],u0.h[1],sA1);
      sA0=fdot2(qa2[2],u0.h[2],sA0); sA1=fdot2(qa2[3],u0.h[3],sA1);
      sA0=fdot2(qa2[4],u1.h[0],sA0); sA1=fdot2(qa2[5],u1.h[1],sA1);
      sB0=fdot2(qb2[0],u0.h[0],sB0); sB1=fdot2(qb2[1],u0.h[1],sB1);
      sB0=fdot2(qb2[2],u0.h[2],sB0); sB1=fdot2(qb2[3],u0.h[3],sB1);
      sB0=fdot2(qb2[4],u1.h[0],sB0); sB1=fdot2(qb2[5],u1.h[1],sB1);
      float p0=__expf(sA0+sA1), p1=__expf(sB0+sB1);
      l0+=p0; l1+=p1;
      const float4* vp=(const float4*)(Vs+k*kHD);
      float4 v0=vp[0], v1=vp[1], v2=vp[2];
      acc0[0].x=fmaf(p0,v0.x,acc0[0].x); acc0[0].y=fmaf(p0,v0.y,acc0[0].y);
      acc0[1].x=fmaf(p0,v0.z,acc0[1].x); acc0[1].y=fmaf(p0,v0.w,acc0[1].y);
      acc0[2].x=fmaf(p0,v1.x,acc0[2].x); acc0[2].y=fmaf(p0,v1.y,acc0[2].y);
      acc0[3].x=fmaf(p0,v1.z,acc0[3].x); acc0[3].y=fmaf(p0,v1.w,acc0[3].y);
      acc0[4].x=fmaf(p0,v2.x,acc0[4].x); acc0[4].y=fmaf(p0,v2.y,acc0[4].y);
      acc0[5].x=fmaf(p0,v2.z,acc0[5].x); acc0[5].y=fmaf(p0,v2.w,acc0[5].y);
      acc1[0].x=fmaf(p1,v0.x,acc1[0].x); acc1[0].y=fmaf(p1,v0.y,acc1[0].y);
      acc1[1].x=fmaf(p1,v0.z,acc1[1].x); acc1[1].y=fmaf(p1,v0.w,acc1[1].y);
      acc1[2].x=fmaf(p1,v1.x,acc1[2].x); acc1[2].y=fmaf(p1,v1.y,acc1[2].y);
      acc1[3].x=fmaf(p1,v1.z,acc1[3].x); acc1[3].y=fmaf(p1,v1.w,acc1[3].y);
      acc1[4].x=fmaf(p1,v2.x,acc1[4].x); acc1[4].y=fmaf(p1,v2.y,acc1[4].y);
      acc1[5].x=fmaf(p1,v2.z,acc1[5].x); acc1[5].y=fmaf(p1,v2.w,acc1[5].y);
    }
    float i0=1.f/l0, i1=1.f/l1;
    long ob=((long)(b*kNH+h))*kS;
    __half2* op0=(__half2*)(p.OP + part*PS + (ob+q0)*kHD);
    __half2* op1=(__half2*)(p.OP + part*PS + (ob+q1)*kHD);
    #pragma unroll
    for(int j=0;j<6;j++){
      op0[j]=__floats2half2_rn(acc0[j].x*i0, acc0[j].y*i0);
      op1[j]=__floats2half2_rn(acc1[j].x*i1, acc1[j].y*i1);
    }
    p.lP[part*LS + ob + q0]=l0;
    p.lP[part*LS + ob + q1]=l1;
  }
}

// ---- phase 3: partial-merge + o-proj + residual + LN1 ----
__device__ __forceinline__ void phase_oproj(unsigned char* arena, const EncP& p){
  __half* W=(__half*)arena;                       // 5376 B
  float* bsh=(float*)(arena+5376);
  float* gs =(float*)(arena+5568);
  float* bs2=(float*)(arena+5760);
  __half2* ot2=(__half2*)(arena+5952);            // 3072
  float* res=(float*)(arena+9024);                // 6144
  float* mrow=(float*)(arena+15168);
  float* rstd=(float*)(arena+15296);
  int tid=threadIdx.x;
  for(int i=tid;i<kD*kD;i+=256){int k=i/48,j=i%48; W[j*56+k]=__float2half(p.wo[i]);}
  if(tid<kD){ bsh[tid]=p.bo[tid]; gs[tid]=p.g1[tid]; bs2[tid]=p.b1g[tid]; }
  const long PS=(long)kB*kNH*kS*kHD, LS=(long)kB*kNH*kS;
  for(long tile=blockIdx.x; tile<2048; tile+=gridDim.x){
    __syncthreads();
    long row0=tile*32;
    for(int i=tid;i<768;i+=256){
      int r=i/24,c=i%24;
      long gq=row0+r; long bb2=gq>>9; long s=gq&511;
      int h=c/6; int d0=(2*c)%12;
      long li=(bb2*kNH+h)*kS+s;
      float l0=p.lP[li], l1=p.lP[li+LS];
      float inv=1.f/(l0+l1);
      long o0=li*(long)kHD+d0;
      float v0=(l0*__half2float(p.OP[o0  ])+l1*__half2float(p.OP[o0  +PS]))*inv;
      float v1=(l0*__half2float(p.OP[o0+1])+l1*__half2float(p.OP[o0+1+PS]))*inv;
      ot2[i]=__floats2half2_rn(v0,v1);
    }
    __syncthreads();
    int r=tid>>3,c0=tid&7;
    __half2 orow[24];
    #pragma unroll
    for(int u=0;u<24;u++) orow[u]=ot2[r*24+u];
    for(int j=c0;j<kD;j+=8){
      float acc=bsh[j]+dot48d(orow,W+j*56);
      res[r*kD+j]=p.X0[row0*kD+r*kD+j]+acc;
    }
    __syncthreads();
    if(tid<32){
      float s=0.f,s2=0.f;
      for(int j=0;j<kD;j++){float v=res[tid*kD+j]; s+=v; s2+=v*v;}
      float m=s*(1.f/kD);
      mrow[tid]=m; rstd[tid]=rsqrtf(s2*(1.f/kD)-m*m+1e-5f);
    }
    __syncthreads();
    for(int i=tid;i<32*kD;i+=256){int r2=i/kD,j=i%kD;
      p.X1[row0*kD+i]=__float2half((res[i]-mrow[r2])*rstd[r2]*gs[j]+bs2[j]);}
  }
}

// ---- phase 4: FFN + residual + LN2 (weights staged once per block) ----
__device__ __forceinline__ void phase_ffn(unsigned char* arena, const EncP& p){
  __half* W1=(__half*)arena;                      // 14336 B
  __half* W2=(__half*)(arena+14336);              // 13056 B
  float* b1s=(float*)(arena+27392);               // 512
  float* b2s=(float*)(arena+27904);               // 192
  float* gs =(float*)(arena+28096);
  float* bs2=(float*)(arena+28288);
  __half* xt=(__half*)(arena+28480);              // 1536
  __half* h1h=(__half*)(arena+30016);             // 4096
  float* res=(float*)(arena+34112);               // 3072
  float* mrow=(float*)(arena+37184);
  float* rstd=(float*)(arena+37248);              // ends 37312
  int tid=threadIdx.x;
  for(int i=tid;i<kD*kFF;i+=256){ int k=i/128,c=i%128; W1[c*56+k]=__float2half(p.w1[i]); }
  for(int i=tid;i<kFF*kD;i+=256){ int u=i/48,j=i%48; W2[j*136+u]=__float2half(p.w2[i]); }
  if(tid<kFF) b1s[tid]=p.b1[tid];
  if(tid<kD){ b2s[tid]=p.b2[tid]; gs[tid]=p.g2[tid]; bs2[tid]=p.b2g[tid]; }
  for(long tile=blockIdx.x; tile<4096; tile+=gridDim.x){
    __syncthreads();
    long row0=tile*16;
    const __half2* Xp=(const __half2*)(p.X1+row0*kD);
    for(int i=tid;i<384;i+=256) ((__half2*)xt)[i]=Xp[i];
    __syncthreads();
    int r=tid>>4,c0=tid&15;
    {
      __half2 xr[24];
      const __half2* xp=(const __half2*)(xt+r*kD);
      #pragma unroll
      for(int u=0;u<24;u++) xr[u]=xp[u];
      for(int c=c0;c<kFF;c+=16){
        float acc=b1s[c]+dot48d(xr,W1+c*56);
        h1h[r*kFF+c]=__float2half(fmaxf(acc,0.f));
      }
    }
    __syncthreads();
    {
      const __half2* hp=(const __half2*)(h1h+r*kFF);
      for(int j=c0;j<kD;j+=16){
        float acc=b2s[j]+dot128d(hp,W2+j*136);
        res[r*kD+j]=__half2float(xt[r*kD+j])+acc;
      }
    }
    __syncthreads();
    if(tid<16){
      float s=0.f,s2=0.f;
      for(int j=0;j<kD;j++){float v=res[tid*kD+j]; s+=v; s2+=v*v;}
      float m=s*(1.f/kD);
      mrow[tid]=m; rstd[tid]=rsqrtf(s2*(1.f/kD)-m*m+1e-5f);
    }
    __syncthreads();
    for(int i=tid;i<16*kD;i+=256){int r2=i/kD,j=i%kD;
      p.Xm[row0*kD+i]=(res[i]-mrow[r2])*rstd[r2]*gs[j]+bs2[j];}
  }
}

// ---- phase 5: cross K/V projection — Kc [b][s][d], Vc [b][d][s] ----
__device__ __forceinline__ void phase_ckv(unsigned char* arena, const EncP& p){
  __half* W=(__half*)arena;                       // 10752 B
  float* bias=(float*)(arena+10752);              // 384
  __half2* xt2=(__half2*)(arena+11136);           // 3072
  int tid=threadIdx.x;
  for(int i=tid;i<2*2304;i+=256){ int m=i/2304,e=i%2304,k=e/48,j=e%48;
    W[m*2688+j*56+k]=__float2half((m?p.cvw:p.ckw)[e]); }
  for(int i=tid;i<2*kD;i+=256){ int m=i/kD,e=i%kD; bias[i]=(m?p.cvb:p.ckb)[e]; }
  for(long tile=blockIdx.x; tile<2048; tile+=gridDim.x){
    __syncthreads();
    long row0=tile*32;
    const float2* Mp=(const float2*)(p.Xm+row0*kD);
    for(int i=tid;i<768;i+=256){ float2 v=Mp[i]; xt2[i]=__floats2half2_rn(v.x,v.y); }
    __syncthreads();
    int r=tid>>3,c0=tid&7;
    __half2 xr[24];
    #pragma unroll
    for(int u=0;u<24;u++) xr[u]=xt2[r*24+u];
    long gr=row0+r; long bb2=gr>>9; long s=gr&511;
    for(int c=c0;c<2*kD;c+=8){
      int m=c/kD,j=c%kD;
      float acc=bias[m*kD+j]+dot48d(xr,W+m*2688+j*56);
      if(m==0) p.Kc[(bb2*kS+s)*kD+j]=__float2half(acc);
      else     p.Vc[(bb2*kD+j)*kS+s]=__float2half(acc);
    }
  }
}

// ---- cooperative mega-kernel: 768 blocks (3/CU: LDS 38.4K<=53K, VGPR capped) ----
__global__ void __launch_bounds__(256,3) k_enc(EncP p){
  __shared__ __align__(16) unsigned char arena[kArena];
  cg::grid_group g = cg::this_grid();
  phase_qkv(arena, p);
  g.sync();
  phase_attn(arena, p);
  g.sync();
  phase_oproj(arena, p);
  g.sync();
  phase_ffn(arena, p);
  g.sync();
  phase_ckv(arena, p);
}

// ---- fallback wrappers (if cooperative launch is rejected) ----
__global__ void __launch_bounds__(256) k_qkv_w(EncP p){
  __shared__ __align__(16) unsigned char arena[kArena]; phase_qkv(arena,p); }
__global__ void __launch_bounds__(256) k_attn_w(EncP p){
  __shared__ __align__(16) unsigned char arena[kArena]; phase_attn(arena,p); }
__global__ void __launch_bounds__(256) k_oproj_w(EncP p){
  __shared__ __align__(16) unsigned char arena[kArena]; phase_oproj(arena,p); }
__global__ void __launch_bounds__(256) k_ffn_w(EncP p){
  __shared__ __align__(16) unsigned char arena[kArena]; phase_ffn(arena,p); }
__global__ void __launch_bounds__(256) k_ckv_w(EncP p){
  __shared__ __align__(16) unsigned char arena[kArena]; phase_ckv(arena,p); }

// ---------------- K7: decoder — R17 structure (measured best; noise band 230-240us) ----------------
struct DecP {
  const float *dec_start, *sbq, *sbk, *sbv, *sbo, *ln1g, *ln1b,
              *cbq, *cbo, *ln2g, *ln2b, *fb1, *fb2, *ln3g, *ln3b, *ow, *ob;
};

__global__ void __launch_bounds__(256,1) k_dec(const __half* __restrict__ KT,
    const __half* __restrict__ VT, const __half* __restrict__ Wg, DecP P,
    float* __restrict__ out){
  __shared__ __align__(16) __half Wl[29824];       // fp16 weights, 58.25 KB
  __shared__ __align__(16) float peT[kT*kD];       // PE table, 12 KB
  __shared__ __align__(16) __half KhH[kNH*kT*kHD]; // self-K cache fp16, 6 KB
  __shared__ __align__(16) float  Vh[kNH*kT*kHD];  // self-V cache fp32, 12 KB
  __shared__ __align__(16) __half qSH[kNH*kHD];    // q by head, fp16
  __shared__ __align__(16) float poS[kNH][kD];     // per-wave cross-o-proj partials
  __shared__ __align__(16) __half xvH[kD], soH[kD], h1H[kD], cqH[kD], h2H[kD];
  __shared__ __align__(16) __half f1H[kFF];
  int tid=threadIdx.x, b=blockIdx.x, wave=tid>>6, lane=tid&63;
  const float rs=0.28867513459481287f;

  for(int i=tid;i<29824/8;i+=256) ((float4*)Wl)[i]=((const float4*)Wg)[i];
  for(int i=tid;i<kT*kD;i+=256){ int tt=i/kD, j=i%kD; peT[i]=pe_val(tt,j); }

  // wave0 per-lane constants (wave0 runs every stage except cross-attn)
  float c_sbq=0,c_sbk=0,c_sbv=0, c_bo=0,c_cbq=0,c_cbo=0,c_fb2=0;
  float g1=0,bb1=0,g2=0,bb2=0,g3=0,bb3=0,c_ow=0, c_fb1a=0,c_fb1b=0, c_ds=0;
  if(wave==0){
    if(lane<kD){
      c_ds=P.dec_start[lane];
      c_sbq=P.sbq[lane]; c_sbk=P.sbk[lane]; c_sbv=P.sbv[lane];
      c_bo=P.sbo[lane]; c_cbq=P.cbq[lane]; c_cbo=P.cbo[lane]; c_fb2=P.fb2[lane];
      g1=P.ln1g[lane]; bb1=P.ln1b[lane];
      g2=P.ln2g[lane]; bb2=P.ln2b[lane];
      g3=P.ln3g[lane]; bb3=P.ln3b[lane];
      c_ow=P.ow[lane];
    }
    c_fb1a=P.fb1[lane]; c_fb1b=P.fb1[lane+64];
  }
  float c_ob=P.ob[0];

  // cross-attn K/V resident in registers: head = wave, 4 key-PAIRS per lane
  // Kc layout [b][s][d]; Vc layout [b][d][s] read as half2 pairs along s.
  __half2 Kr2[4][2][6], Vr2[4][kHD];   // 48 + 48 VGPRs
  {
    const __half* Kb = KT + (long)b*kS*kD;
    const __half2* Vb = (const __half2*)VT + (long)b*kD*(kS/2);
    #pragma unroll
    for(int i=0;i<4;i++){
      int sp = lane + 64*i;
      #pragma unroll
      for(int e=0;e<2;e++){
        const __half2* kp=(const __half2*)(Kb + (long)(2*sp+e)*kD + wave*kHD);
        #pragma unroll
        for(int c=0;c<6;c++) Kr2[i][e][c]=kp[c];
      }
      #pragma unroll
      for(int u=0;u<kHD;u++) Vr2[i][u]=Vb[(wave*kHD+u)*(kS/2)+sp];
    }
  }
  __syncthreads();

  // peel t=0's A0: wave0 publishes x0
  float xv=0;
  if(wave==0 && lane<kD){ xv=c_ds+peT[lane]; xvH[lane]=__float2half(xv); }
  __syncthreads();

  float h1=0, h2=0, yacc=0;
  for(int t=0;t<kT;t++){
    // ======== A: wave0-only segment (wsync handoffs, no block barriers) ========
    if(wave==0){
      // A1: qkv — x loaded into regs ONCE, reused across 3 dots
      if(lane<kD){
        __half2 xr[24];
        const __half2* xp=(const __half2*)xvH;
        #pragma unroll
        for(int u=0;u<24;u++) xr[u]=xp[u];
        float qv=c_sbq+dot48d(xr, Wl + 0*2688 + lane*56);
        float kv=c_sbk+dot48d(xr, Wl + 1*2688 + lane*56);
        float vv=c_sbv+dot48d(xr, Wl + 2*2688 + lane*56);
        int hh=lane/kHD, dd=lane%kHD;
        qSH[lane]=__float2half(qv);
        KhH[(hh*kT+t)*kHD+dd]=__float2half(kv);
        Vh[(hh*kT+t)*kHD+dd]=vv;
      }
      wsync();
      // A2: self-attn, 4 heads in one wave: lane = head*16 + keygroup
      {
        int hh=lane>>4, g=lane&15;
        __half2 q2[6];
        const __half2* qp=(const __half2*)qSH + hh*6;
        #pragma unroll
        for(int c=0;c<6;c++) q2[c]=qp[c];
        float l=0.f, acc[kHD];
        #pragma unroll
        for(int u=0;u<kHD;u++) acc[u]=0.f;
        #pragma unroll
        for(int kk=0;kk<4;kk++){
          int key=g+16*kk;
          if(key<=t){
            const __half2* kp=(const __half2*)KhH + (hh*kT+key)*6;
            float a0=0.f,a1=0.f;
            a0=fdot2(q2[0],kp[0],a0); a1=fdot2(q2[1],kp[1],a1);
            a0=fdot2(q2[2],kp[2],a0); a1=fdot2(q2[3],kp[3],a1);
            a0=fdot2(q2[4],kp[4],a0); a1=fdot2(q2[5],kp[5],a1);
            float p=__expf((a0+a1)*rs);
            l+=p;
            const float4* vp=(const float4*)(Vh+(hh*kT+key)*kHD);
            float4 v0=vp[0], v1=vp[1], v2=vp[2];
            float vr[kHD]={v0.x,v0.y,v0.z,v0.w,v1.x,v1.y,v1.z,v1.w,v2.x,v2.y,v2.z,v2.w};
            #pragma unroll
            for(int u=0;u<kHD;u++) acc[u]+=p*vr[u];
          }
        }
        l=rowsum16(l);
        #pragma unroll
        for(int u=0;u<kHD;u++) acc[u]=rowsum16(acc[u]);
        if(g==15){
          float inv=1.f/l;
          #pragma unroll
          for(int u=0;u<6;u++)
            ((__half2*)soH)[hh*6+u]=__floats2half2_rn(acc[2*u]*inv, acc[2*u+1]*inv);
        }
      }
      wsync();
      // A3: self o-proj + residual + LN1
      {
        float rr=0.f;
        if(lane<kD)
          rr=xv+c_bo+dot48d((const __half2*)soH, Wl+8064+lane*56);
        float s1=wsum(rr), s2=wsum(rr*rr);
        float mean=s1*(1.f/48.f);
        float rstd=rsqrtf(s2*(1.f/48.f)-mean*mean+1e-5f);
        h1=0;
        if(lane<kD){ h1=(rr-mean)*rstd*g1+bb1; h1H[lane]=__float2half(h1); }
      }
      wsync();
      // A4: cross-q
      if(lane<kD)
        cqH[lane]=__float2half(c_cbq+dot48d((const __half2*)h1H, Wl+10752+lane*56));
    }
    __syncthreads();                                   // B1: cqH -> all waves
    // ======== X: cross-attn on all 4 waves (head = wave); fp32 P, no max-sub;
    //             ends with per-wave PARTIAL cross-o-proj into poS ========
    {
      __half2 q2[6];
      #pragma unroll
      for(int c=0;c<6;c++) q2[c]=((const __half2*)cqH)[wave*6+c];
      float s[8];
      #pragma unroll
      for(int i=0;i<4;i++){
        #pragma unroll
        for(int e=0;e<2;e++){
          float a0=0.f,a1=0.f;
          const __half2* kp=Kr2[i][e];
          a0=fdot2(q2[0],kp[0],a0); a1=fdot2(q2[1],kp[1],a1);
          a0=fdot2(q2[2],kp[2],a0); a1=fdot2(q2[3],kp[3],a1);
          a0=fdot2(q2[4],kp[4],a0); a1=fdot2(q2[5],kp[5],a1);
          s[2*i+e]=(a0+a1)*rs;
        }
      }
      float p32[8], l=0.f;
      #pragma unroll
      for(int j=0;j<8;j++){ p32[j]=__expf(s[j]); l+=p32[j]; }
      l=wsum(l);
      float inv=1.f/l;
      __half2 ph[4];
      #pragma unroll
      for(int i=0;i<4;i++) ph[i]=__floats2half2_rn(p32[2*i]*inv, p32[2*i+1]*inv);
      float acc[kHD];
      #pragma unroll
      for(int u=0;u<kHD;u++) acc[u]=0.f;
      #pragma unroll
      for(int i=0;i<4;i++){
        #pragma unroll
        for(int u=0;u<kHD;u++) acc[u]=fdot2(ph[i],Vr2[i][u],acc[u]);
      }
      #pragma unroll
      for(int u=0;u<kHD;u++) acc[u]=wsum(acc[u]);
      // partial o-proj for this head (moves dot-work BEFORE barrier B2)
      if(lane<kD){
        __half2 ah[6];
        #pragma unroll
        for(int u=0;u<6;u++) ah[u]=__floats2half2_rn(acc[2*u],acc[2*u+1]);
        const __half2* wp=(const __half2*)(Wl+13440+lane*56+wave*kHD);
        float p0=0.f,p1=0.f;
        p0=fdot2(ah[0],wp[0],p0); p1=fdot2(ah[1],wp[1],p1);
        p0=fdot2(ah[2],wp[2],p0); p1=fdot2(ah[3],wp[3],p1);
        p0=fdot2(ah[4],wp[4],p0); p1=fdot2(ah[5],wp[5],p1);
        poS[wave][lane]=p0+p1;
      }
    }
    __syncthreads();                                   // B2: poS -> wave0
    // ======== C: wave0-only segment ========
    if(wave==0){
      // C0: cross o-proj = sum of 4 per-head partials; + residual + LN2
      {
        float rr=0.f;
        if(lane<kD)
          rr=h1+c_cbo+((poS[0][lane]+poS[1][lane])+(poS[2][lane]+poS[3][lane]));
        float s1=wsum(rr), s2=wsum(rr*rr);
        float mean=s1*(1.f/48.f);
        float rstd=rsqrtf(s2*(1.f/48.f)-mean*mean+1e-5f);
        h2=0;
        if(lane<kD){ h2=(rr-mean)*rstd*g2+bb2; h2H[lane]=__float2half(h2); }
      }
      wsync();
      // C1: FFN1 — 2 cols per lane (pipelined)
      {
        float a=c_fb1a+dot48d((const __half2*)h2H, Wl+16128+lane*56);
        float bcol=c_fb1b+dot48d((const __half2*)h2H, Wl+16128+(lane+64)*56);
        f1H[lane]=__float2half(fmaxf(a,0.f));
        f1H[lane+64]=__float2half(fmaxf(bcol,0.f));
      }
      wsync();
      // C2: FFN2 + residual + LN3; fused next-x publish; y into reg buffer
      {
        float rr=0.f;
        if(lane<kD)
          rr=h2+c_fb2+dot128d((const __half2*)f1H, Wl+23296+lane*136);
        float s1=wsum(rr), s2=wsum(rr*rr);
        float mean=s1*(1.f/48.f);
        float rstd=rsqrtf(s2*(1.f/48.f)-mean*mean+1e-5f);
        float cv=0.f;
        if(lane<kD) cv=(rr-mean)*rstd*g3+bb3;
        // publish x_{t+1} FIRST (hides under the y-reduction)
        if(lane<kD && t+1<kT){ xv=cv+peT[(t+1)*kD+lane]; xvH[lane]=__float2half(xv); }
        wsync();
        float y=wsum(cv*c_ow);
        if(lane==t) yacc=y;
      }
    }
  }
  if(wave==0) out[(long)b*kT+lane]=yacc+c_ob;
}

extern "C" void kernel_launch(void* const* d_in, const int* in_sizes, int n_in,
                              void* d_out, int out_size, void* d_ws, size_t ws_size,
                              hipStream_t stream){
  // ws layout: Wh fp16 (64KB) | A fp32 NB | H1/H2/H3 fp16 NB | OP fp16 2*NB | lP fp32 2*BHS
  // total ~46.2 MB
  float* ws = (float*)d_ws;
  __half* Wh = (__half*)ws;
  const size_t NB = (size_t)kB*kS*kD;     // 3,145,728
  const size_t BHS = (size_t)kB*kNH*kS;   // 262,144
  float*  A  = ws + 16384;
  __half* H1 = (__half*)(A + NB);
  __half* H2 = H1 + NB;
  __half* H3 = H2 + NB;
  __half* OP = H3 + NB;
  float*  lP = (float*)(OP + 2*NB);

  EncP e;
  e.src=(const float*)d_in[0]; e.in_w=(const float*)d_in[1]; e.in_b=(const float*)d_in[2]; e.X0=A;
  e.wq=(const float*)d_in[4]; e.bq=(const float*)d_in[5];
  e.wk=(const float*)d_in[6]; e.bk=(const float*)d_in[7];
  e.wv=(const float*)d_in[8]; e.bv=(const float*)d_in[9];
  e.Q=H1; e.K=H2; e.V=H3;
  e.swq=(const float*)d_in[20]; e.swk=(const float*)d_in[22]; e.swv=(const float*)d_in[24];
  e.swo=(const float*)d_in[26]; e.cwq=(const float*)d_in[30]; e.cwo=(const float*)d_in[36];
  e.dw1=(const float*)d_in[40]; e.dw2=(const float*)d_in[42]; e.Wh=Wh;
  e.OP=OP; e.lP=lP;
  e.wo=(const float*)d_in[10]; e.bo=(const float*)d_in[11];
  e.g1=(const float*)d_in[12]; e.b1g=(const float*)d_in[13]; e.X1=H2;  // K dead after attn
  e.w1=(const float*)d_in[14]; e.b1=(const float*)d_in[15];
  e.w2=(const float*)d_in[16]; e.b2=(const float*)d_in[17];
  e.g2=(const float*)d_in[18]; e.b2g=(const float*)d_in[19]; e.Xm=A;   // X0 dead after oproj
  e.ckw=(const float*)d_in[32]; e.ckb=(const float*)d_in[33];
  e.cvw=(const float*)d_in[34]; e.cvb=(const float*)d_in[35];
  e.Kc=H1; e.Vc=H3;                                                    // Q,V dead after attn

  void* args[] = { (void*)&e };
  hipError_t err = hipLaunchCooperativeKernel((void*)k_enc, dim3(768), dim3(256),
                                              args, 0, stream);
  if(err != hipSuccess){
    // fallback: separate launches (grid-stride loops handle larger grids)
    k_qkv_w  <<<2048,256,0,stream>>>(e);
    k_attn_w <<<1024,256,0,stream>>>(e);
    k_oproj_w<<<2048,256,0,stream>>>(e);
    k_ffn_w  <<<4096,256,0,stream>>>(e);
    k_ckv_w  <<<2048,256,0,stream>>>(e);
  }

  DecP P;
  P.dec_start=(const float*)d_in[3];
  P.sbq=(const float*)d_in[21]; P.sbk=(const float*)d_in[23]; P.sbv=(const float*)d_in[25]; P.sbo=(const float*)d_in[27];
  P.ln1g=(const float*)d_in[28]; P.ln1b=(const float*)d_in[29];
  P.cbq=(const float*)d_in[31]; P.cbo=(const float*)d_in[37];
  P.ln2g=(const float*)d_in[38]; P.ln2b=(const float*)d_in[39];
  P.fb1=(const float*)d_in[41]; P.fb2=(const float*)d_in[43];
  P.ln3g=(const float*)d_in[44]; P.ln3b=(const float*)d_in[45];
  P.ow=(const float*)d_in[46]; P.ob=(const float*)d_in[47];
  k_dec<<<kB,256,0,stream>>>(H1,H3,Wh,P,(float*)d_out);
}

// Round 12
// 568.806 us; speedup vs baseline: 1.6989x; 1.6989x over previous
//
#include <hip/hip_runtime.h>
#include <hip/hip_bf16.h>
#include <hip/hip_fp16.h>

// Inputs/outputs are FP32 (verified R3/R6).
// R10: KV-in-regs OR weights-in-regs — never both (compiler demotes silently).
// R11: redundant all-wave broadcast stages LOSE. R12: dot2+fp16 LDS; latency-bound.
// R13: wall time = per-step critical path. R14: mega-wave0 + 2 barriers -> 236us;
//   chip runs ~1.1GHz at this occupancy (DVFS).
// R15: weights-in-VGPR regressed. R16: launch gap ~10us/kernel.
// R17: encoder 3-way fusion regressed; k_dec cross-o-proj partials won.
// R18: attn 2-way split -> issue-bound. R19: best = 567.3us (attn diet + prep merge).
// R20 lesson: cooperative mega-encoder REGRESSED BADLY (538us vs ~270): 768-block
//   grid + grid.sync = load imbalance serialization + capped occupancy. Launch gaps
//   cannot be harvested via persistent blocks on this chip.
// R21: revert to R19; fold k_ckv into k_ffn_ln epilogue (k_ffn_ckv): mem never
//   touches global, -1 launch, -25MB traffic. LDS ~50KB -> 3 blocks/CU (12 waves/CU
//   preserved).

constexpr int kB  = 128;
constexpr int kS  = 512;
constexpr int kT  = 64;
constexpr int kD  = 48;
constexpr int kFF = 128;
constexpr int kNH = 4;
constexpr int kHD = 12;

__device__ __forceinline__ void wsync(){
  __builtin_amdgcn_wave_barrier();
  asm volatile("" ::: "memory");
}

// ---- DPP wave64 reductions (VALU-speed) ----
template<int CTRL,int RM,int BM,bool BC>
__device__ __forceinline__ float dppmov(float x, float old){
  return __builtin_bit_cast(float, __builtin_amdgcn_update_dpp(
      __builtin_bit_cast(int, old), __builtin_bit_cast(int, x), CTRL, RM, BM, BC));
}
// sum across 64 lanes, result uniform in all lanes
__device__ __forceinline__ float wsum(float x){
  x += dppmov<0x111,0xf,0xf,true>(x, 0.f);   // row_shr:1
  x += dppmov<0x112,0xf,0xf,true>(x, 0.f);   // row_shr:2
  x += dppmov<0x114,0xf,0xf,true>(x, 0.f);   // row_shr:4
  x += dppmov<0x118,0xf,0xf,true>(x, 0.f);   // row_shr:8
  x += dppmov<0x142,0xa,0xf,true>(x, 0.f);   // row_bcast:15 -> rows 1,3
  x += dppmov<0x143,0xc,0xf,true>(x, 0.f);   // row_bcast:31 -> rows 2,3
  return __builtin_bit_cast(float, __builtin_amdgcn_readlane(__builtin_bit_cast(int, x), 63));
}
// sum within each 16-lane row; result valid at lane 15 of each row
__device__ __forceinline__ float rowsum16(float x){
  x += dppmov<0x111,0xf,0xf,true>(x, 0.f);
  x += dppmov<0x112,0xf,0xf,true>(x, 0.f);
  x += dppmov<0x114,0xf,0xf,true>(x, 0.f);
  x += dppmov<0x118,0xf,0xf,true>(x, 0.f);
  return x;
}

// pe[p, 2i] = sin(p * exp(-2i*ln(10000)/48)), pe[p, 2i+1] = cos(...)
__device__ __forceinline__ float pe_val(int p, int j){   // precise (table init)
  int i = j >> 1;
  float f = expf(-0.19188209108283716f * (float)(2*i));
  float a = (float)p * f;
  return (j & 1) ? cosf(a) : sinf(a);
}
__device__ __forceinline__ float pe_fast(int p, int j){  // encoder embed
  int i = j >> 1;
  float f = __expf(-0.19188209108283716f * (float)(2*i));
  float a = (float)p * f;
  return (j & 1) ? __cosf(a) : __sinf(a);
}

// ---- packed fp16 dot: d = a.x*b.x + a.y*b.y + c (v_dot2_f32_f16) ----
typedef _Float16 h2v __attribute__((ext_vector_type(2)));
union H2U { __half2 h; h2v v; };
__device__ __forceinline__ float fdot2(__half2 a, __half2 b, float c){
#if __has_builtin(__builtin_amdgcn_fdot2)
  H2U ua, ub; ua.h=a; ub.h=b;
  return __builtin_amdgcn_fdot2(ua.v, ub.v, c, false);
#else
  float2 fa=__half22float2(a), fb=__half22float2(b);
  return fmaf(fa.y, fb.y, fmaf(fa.x, fb.x, c));
#endif
}
union F4H2 { float4 f; __half2 h[4]; };

// 48-dot, x (LDS or reg array) vs w (LDS), 4 accumulator chains
__device__ __forceinline__ float dot48d(const __half2* x, const __half* w){
  const __half2* w2=(const __half2*)w;
  float a0=0.f,a1=0.f,a2=0.f,a3=0.f;
  #pragma unroll
  for(int c=0;c<6;c++){
    a0=fdot2(x[4*c+0],w2[4*c+0],a0);
    a1=fdot2(x[4*c+1],w2[4*c+1],a1);
    a2=fdot2(x[4*c+2],w2[4*c+2],a2);
    a3=fdot2(x[4*c+3],w2[4*c+3],a3);
  }
  return (a0+a1)+(a2+a3);
}
// 128-dot, 8 accumulator chains
__device__ __forceinline__ float dot128d(const __half2* x, const __half* w){
  const __half2* w2=(const __half2*)w;
  float a0=0.f,a1=0.f,a2=0.f,a3=0.f,a4=0.f,a5=0.f,a6=0.f,a7=0.f;
  #pragma unroll
  for(int c=0;c<8;c++){
    a0=fdot2(x[8*c+0],w2[8*c+0],a0);
    a1=fdot2(x[8*c+1],w2[8*c+1],a1);
    a2=fdot2(x[8*c+2],w2[8*c+2],a2);
    a3=fdot2(x[8*c+3],w2[8*c+3],a3);
    a4=fdot2(x[8*c+4],w2[8*c+4],a4);
    a5=fdot2(x[8*c+5],w2[8*c+5],a5);
    a6=fdot2(x[8*c+6],w2[8*c+6],a6);
    a7=fdot2(x[8*c+7],w2[8*c+7],a7);
  }
  return ((a0+a1)+(a2+a3))+((a4+a5)+(a6+a7));
}

// ---------------- K2: FUSED embed + encoder QKV projection (+ k_prep blocks) ----------------
// blocks [0,2048): qkv tiles. blocks [2048,2150): decoder weight prep (independent).
__global__ void __launch_bounds__(256) k_qkv(const float* __restrict__ src,
    const float* __restrict__ in_w, const float* __restrict__ in_b,
    float* __restrict__ X0,
    const float* __restrict__ wq, const float* __restrict__ bq,
    const float* __restrict__ wk, const float* __restrict__ bk,
    const float* __restrict__ wv, const float* __restrict__ bv,
    __half* __restrict__ Q, __half* __restrict__ K, __half* __restrict__ V,
    const float* __restrict__ swq, const float* __restrict__ swk,
    const float* __restrict__ swv, const float* __restrict__ swo,
    const float* __restrict__ cwq, const float* __restrict__ cwo,
    const float* __restrict__ dw1, const float* __restrict__ dw2,
    __half* __restrict__ Wh){
  if(blockIdx.x >= 2048){
    // ---- k_prep: decoder weights -> padded fp16 column-major (see Wh map) ----
    int idx=(blockIdx.x-2048)*256+threadIdx.x;
    if(idx>=26112) return;
    if(idx<13824){
      int m=idx/2304, e=idx%2304, j=e/48, k=e%48;
      const float* w = (m==0)?swq:((m==1)?swk:((m==2)?swv:((m==3)?swo:((m==4)?cwq:cwo))));
      Wh[m*2688 + j*56 + k] = __float2half(w[k*48+j]);
    } else if(idx<19968){
      int e=idx-13824, c=e/48, k=e%48;
      Wh[16128 + c*56 + k] = __float2half(dw1[k*128+c]);
    } else {
      int e=idx-19968, j=e/128, u=e%128;
      Wh[23296 + j*136 + u] = __float2half(dw2[u*48+j]);
    }
    return;
  }
  __shared__ __align__(16) __half W[3*2688];     // col stride 56 halves
  __shared__ __align__(16) float bias[3*kD];
  __shared__ __align__(16) __half2 xt2[32*24];
  int tid = threadIdx.x;
  for (int i=tid;i<3*2304;i+=256){ int m=i/2304, e=i%2304, k=e/48, j=e%48;
    const float* w = (m==0)?wq:((m==1)?wk:wv);
    W[m*2688 + j*56 + k] = __float2half(w[e]); }
  for (int i=tid;i<3*kD;i+=256){ int m=i/kD,e=i%kD;
    const float* w=(m==0)?bq:((m==1)?bk:bv); bias[i]=w[e]; }
  long row0 = (long)blockIdx.x*32;
  const float sc = 6.928203230275509f;
  // fused embed: x = (src*in_w+in_b)*sqrt(d) + pe; fp32 -> X0, fp16 -> LDS
  for (int i=tid;i<768;i+=256){
    int r=i/24, c=i%24;
    long gr=row0+r; int s=(int)(gr&511);
    float sv=src[gr];
    float va=(sv*in_w[2*c  ]+in_b[2*c  ])*sc + pe_fast(s,2*c  );
    float vb=(sv*in_w[2*c+1]+in_b[2*c+1])*sc + pe_fast(s,2*c+1);
    ((float2*)X0)[row0*24 + i]=make_float2(va,vb);
    xt2[i]=__floats2half2_rn(va,vb);
  }
  __syncthreads();
  int r = tid>>3, c0 = tid&7;
  __half2 xr[24];
  #pragma unroll
  for(int u=0;u<24;u++) xr[u]=xt2[r*24+u];
  const float rs = 0.28867513459481287f;   // folded into Q (consumed only by attn)
  for (int c=c0; c<3*kD; c+=8){
    int m=c/kD, j=c%kD;
    float acc = bias[m*kD+j] + dot48d(xr, W + m*2688 + j*56);
    if(m==0) acc*=rs;
    __half* o = (m==0)?Q:((m==1)?K:V);
    o[(row0+r)*kD+j]=__float2half(acc);
  }
}

// ---------------- K3: encoder attention — 2-way key split, wide LDS reads ----------------
// grid 1024: blockIdx = (b*kNH+h)*2+part. K rows padded to 8 half2 (32B) -> 2x b128;
// V rows read as 3x float4. Q pre-scaled by 1/sqrt(hd) in k_qkv.
__global__ void __launch_bounds__(256) k_attn(const __half* __restrict__ Q,
      const __half* __restrict__ K, const __half* __restrict__ V,
      __half* __restrict__ OP, float* __restrict__ lP){
  int part = blockIdx.x & 1;
  int bh = blockIdx.x >> 1;
  int b = bh / kNH, h = bh % kNH;
  __shared__ __align__(16) __half2 Ks2[256*8];  // 8 KB (stride 8, cols 6-7 unused)
  __shared__ __align__(16) float   Vs[256*kHD]; // 12 KB
  int tid = threadIdx.x;
  long base = ((long)b*kS)*kD + h*kHD;
  int k0 = part<<8;
  for (int i=tid;i<256*6;i+=256){ int r=i/6, c=i%6;
    Ks2[r*8+c]=*(const __half2*)&K[base+(long)(k0+r)*kD+2*c]; }
  for (int i=tid;i<256*kHD;i+=256){ int r=i/kHD, d=i%kHD;
    Vs[i]=__half2float(V[base+(long)(k0+r)*kD+d]); }
  int q0 = tid, q1 = tid+256;
  __half2 qa2[6], qb2[6];
  {
    const __half2* qp0=(const __half2*)(Q+base+(long)q0*kD);
    const __half2* qp1=(const __half2*)(Q+base+(long)q1*kD);
    #pragma unroll
    for(int c=0;c<6;c++){ qa2[c]=qp0[c]; qb2[c]=qp1[c]; }
  }
  __syncthreads();
  float2 acc0[6], acc1[6];
  #pragma unroll
  for(int j=0;j<6;j++){ acc0[j]=make_float2(0.f,0.f); acc1[j]=make_float2(0.f,0.f); }
  float l0=0.f, l1=0.f;
  for(int k=0;k<256;k++){
    const float4* kp4=(const float4*)(Ks2+k*8);   // broadcast, 2x b128
    F4H2 u0,u1; u0.f=kp4[0]; u1.f=kp4[1];
    float sA0=0.f,sA1=0.f,sB0=0.f,sB1=0.f;
    sA0=fdot2(qa2[0],u0.h[0],sA0); sA1=fdot2(qa2[1],u0.h[1],sA1);
    sA0=fdot2(qa2[2],u0.h[2],sA0); sA1=fdot2(qa2[3],u0.h[3],sA1);
    sA0=fdot2(qa2[4],u1.h[0],sA0); sA1=fdot2(qa2[5],u1.h[1],sA1);
    sB0=fdot2(qb2[0],u0.h[0],sB0); sB1=fdot2(qb2[1],u0.h[1],sB1);
    sB0=fdot2(qb2[2],u0.h[2],sB0); sB1=fdot2(qb2[3],u0.h[3],sB1);
    sB0=fdot2(qb2[4],u1.h[0],sB0); sB1=fdot2(qb2[5],u1.h[1],sB1);
    float p0=__expf(sA0+sA1), p1=__expf(sB0+sB1);
    l0+=p0; l1+=p1;
    const float4* vp=(const float4*)(Vs+k*kHD);   // broadcast, 3x b128
    float4 v0=vp[0], v1=vp[1], v2=vp[2];
    acc0[0].x=fmaf(p0,v0.x,acc0[0].x); acc0[0].y=fmaf(p0,v0.y,acc0[0].y);
    acc0[1].x=fmaf(p0,v0.z,acc0[1].x); acc0[1].y=fmaf(p0,v0.w,acc0[1].y);
    acc0[2].x=fmaf(p0,v1.x,acc0[2].x); acc0[2].y=fmaf(p0,v1.y,acc0[2].y);
    acc0[3].x=fmaf(p0,v1.z,acc0[3].x); acc0[3].y=fmaf(p0,v1.w,acc0[3].y);
    acc0[4].x=fmaf(p0,v2.x,acc0[4].x); acc0[4].y=fmaf(p0,v2.y,acc0[4].y);
    acc0[5].x=fmaf(p0,v2.z,acc0[5].x); acc0[5].y=fmaf(p0,v2.w,acc0[5].y);
    acc1[0].x=fmaf(p1,v0.x,acc1[0].x); acc1[0].y=fmaf(p1,v0.y,acc1[0].y);
    acc1[1].x=fmaf(p1,v0.z,acc1[1].x); acc1[1].y=fmaf(p1,v0.w,acc1[1].y);
    acc1[2].x=fmaf(p1,v1.x,acc1[2].x); acc1[2].y=fmaf(p1,v1.y,acc1[2].y);
    acc1[3].x=fmaf(p1,v1.z,acc1[3].x); acc1[3].y=fmaf(p1,v1.w,acc1[3].y);
    acc1[4].x=fmaf(p1,v2.x,acc1[4].x); acc1[4].y=fmaf(p1,v2.y,acc1[4].y);
    acc1[5].x=fmaf(p1,v2.z,acc1[5].x); acc1[5].y=fmaf(p1,v2.w,acc1[5].y);
  }
  // self-normalized partials (fp16-safe: |acc/l| <= max|V|)
  float i0=1.f/l0, i1=1.f/l1;
  const long PS=(long)kB*kNH*kS*kHD, LS=(long)kB*kNH*kS;
  long ob=((long)(b*kNH+h))*kS;
  __half2* op0=(__half2*)(OP + part*PS + (ob+q0)*kHD);
  __half2* op1=(__half2*)(OP + part*PS + (ob+q1)*kHD);
  #pragma unroll
  for(int j=0;j<6;j++){
    op0[j]=__floats2half2_rn(acc0[j].x*i0, acc0[j].y*i0);
    op1[j]=__floats2half2_rn(acc1[j].x*i1, acc1[j].y*i1);
  }
  lP[part*LS + ob + q0]=l0;
  lP[part*LS + ob + q1]=l1;
}

// ---------------- K4: o-proj + residual + LN; merges attn partials in staging ----------------
__global__ void __launch_bounds__(256) k_oproj_ln(const float* __restrict__ Xres,
      const __half* __restrict__ OP, const float* __restrict__ lP,
      const float* __restrict__ wo, const float* __restrict__ bo,
      const float* __restrict__ g, const float* __restrict__ bb,
      __half* __restrict__ Xout){
  __shared__ __align__(16) __half W[kD*56];
  __shared__ float bsh[kD], gs[kD], bs2[kD];
  __shared__ __align__(16) float res[32*kD];
  __shared__ __align__(16) __half2 ot2[32*24];
  __shared__ float mrow[32], rstd[32];
  int tid=threadIdx.x;
  for(int i=tid;i<kD*kD;i+=256){ int k=i/48, j=i%48; W[j*56+k]=__float2half(wo[i]); }
  if(tid<kD){ bsh[tid]=bo[tid]; gs[tid]=g[tid]; bs2[tid]=bb[tid]; }
  long row0=(long)blockIdx.x*32;
  // merge the two attn partials: o = (l0*o0 + l1*o1)/(l0+l1)
  const long PS=(long)kB*kNH*kS*kHD, LS=(long)kB*kNH*kS;
  for(int i=tid;i<768;i+=256){
    int r=i/24, c=i%24;
    long gq=row0+r; long bb2=gq>>9; long s=gq&511;
    int h=c/6; int d0=(2*c)%12;
    long li=(bb2*kNH+h)*kS+s;
    float l0=lP[li], l1=lP[li+LS];
    float inv=1.f/(l0+l1);
    long o0=li*(long)kHD+d0;
    float v0=(l0*__half2float(OP[o0  ]) + l1*__half2float(OP[o0  +PS]))*inv;
    float v1=(l0*__half2float(OP[o0+1]) + l1*__half2float(OP[o0+1+PS]))*inv;
    ot2[i]=__floats2half2_rn(v0,v1);
  }
  __syncthreads();
  int r=tid>>3, c0=tid&7;
  __half2 orow[24];
  #pragma unroll
  for(int u=0;u<24;u++) orow[u]=ot2[r*24+u];
  for(int j=c0;j<kD;j+=8){
    float acc=bsh[j]+dot48d(orow, W+j*56);
    res[r*kD+j]=Xres[row0*kD + r*kD + j]+acc;
  }
  __syncthreads();
  if(tid<32){
    float s=0.f, s2=0.f;
    for(int j=0;j<kD;j++){ float v=res[tid*kD+j]; s+=v; s2+=v*v; }
    float m=s*(1.f/kD);
    mrow[tid]=m; rstd[tid]=rsqrtf(s2*(1.f/kD)-m*m+1e-5f);
  }
  __syncthreads();
  for(int i=tid;i<32*kD;i+=256){int r2=i/kD,j=i%kD;
    Xout[row0*kD+i]=__float2half((res[i]-mrow[r2])*rstd[r2]*gs[j]+bs2[j]); }
}

// ---------------- K5: FFN + residual + LN2 + cross-K/V projection (R21 fusion) ----------------
// mem (LN2-out) never leaves LDS; writes Kc [b][s][d] and Vc [b][d][s] directly.
__global__ void __launch_bounds__(256) k_ffn_ckv(const __half* __restrict__ Xin,
   const float* __restrict__ w1, const float* __restrict__ b1,
   const float* __restrict__ w2, const float* __restrict__ b2,
   const float* __restrict__ g, const float* __restrict__ bb,
   const float* __restrict__ ckw, const float* __restrict__ ckb,
   const float* __restrict__ cvw, const float* __restrict__ cvb,
   __half* __restrict__ Kc, __half* __restrict__ Vc){
  __shared__ __align__(16) __half W1[kFF*56];     // 14336 B
  __shared__ __align__(16) __half W2[kD*136];     // 13056 B
  __shared__ __align__(16) __half Wkv[2*2688];    // 10752 B
  __shared__ float b1s[kFF], b2s[kD], gs[kD], bs2[kD], bks[kD], bvs[kD];
  __shared__ __align__(16) __half xt[16*kD];
  __shared__ __align__(16) __half h1h[16*kFF];
  __shared__ __align__(16) float res[16*kD];
  __shared__ __align__(16) __half memh[16*kD];
  __shared__ float mrow[16], rstd[16];
  int tid=threadIdx.x;
  for(int i=tid;i<kD*kFF;i+=256){ int k=i/128, c=i%128; W1[c*56+k]=__float2half(w1[i]); }
  for(int i=tid;i<kFF*kD;i+=256){ int u=i/48, j=i%48; W2[j*136+u]=__float2half(w2[i]); }
  for(int i=tid;i<2*2304;i+=256){ int m=i/2304, e=i%2304, k=e/48, j=e%48;
    Wkv[m*2688 + j*56 + k]=__float2half((m?cvw:ckw)[e]); }
  if(tid<kFF) b1s[tid]=b1[tid];
  if(tid<kD){ b2s[tid]=b2[tid]; gs[tid]=g[tid]; bs2[tid]=bb[tid];
    bks[tid]=ckb[tid]; bvs[tid]=cvb[tid]; }
  long row0=(long)blockIdx.x*16;
  const __half2* Xp=(const __half2*)(Xin+row0*kD);
  for(int i=tid;i<384;i+=256) ((__half2*)xt)[i]=Xp[i];
  __syncthreads();
  int r=tid>>4, c0=tid&15;
  {
    __half2 xr[24];
    const __half2* xp=(const __half2*)(xt + r*kD);
    #pragma unroll
    for(int u=0;u<24;u++) xr[u]=xp[u];
    for(int c=c0;c<kFF;c+=16){
      float acc=b1s[c]+dot48d(xr, W1+c*56);
      h1h[r*kFF+c]=__float2half(fmaxf(acc,0.f));
    }
  }
  __syncthreads();
  {
    const __half2* hp=(const __half2*)(h1h + r*kFF);
    for(int j=c0;j<kD;j+=16){
      float acc=b2s[j]+dot128d(hp, W2+j*136);
      res[r*kD+j]=__half2float(xt[r*kD+j])+acc;
    }
  }
  __syncthreads();
  if(tid<16){
    float s=0.f, s2=0.f;
    for(int j=0;j<kD;j++){ float v=res[tid*kD+j]; s+=v; s2+=v*v; }
    float m=s*(1.f/kD);
    mrow[tid]=m; rstd[tid]=rsqrtf(s2*(1.f/kD)-m*m+1e-5f);
  }
  __syncthreads();
  for(int i=tid;i<16*kD;i+=256){int r2=i/kD,j=i%kD;
    memh[i]=__float2half((res[i]-mrow[r2])*rstd[r2]*gs[j]+bs2[j]); }
  __syncthreads();
  // cross K/V projection from memh (6 cols per thread)
  {
    __half2 mr[24];
    const __half2* mp=(const __half2*)(memh + r*kD);
    #pragma unroll
    for(int u=0;u<24;u++) mr[u]=mp[u];
    long gr=row0+r; long bb2=gr>>9; long s=gr&511;
    for(int c=c0;c<2*kD;c+=16){
      int m=c/kD, j=c%kD;
      float acc=(m?bvs:bks)[j]+dot48d(mr, Wkv+m*2688+j*56);
      if(m==0) Kc[(bb2*kS+s)*kD + j]=__float2half(acc);     // [b][s][d]
      else     Vc[(bb2*kD+j)*kS + s]=__float2half(acc);     // [b][d][s]
    }
  }
}

// ---------------- K7: decoder — R17 structure (measured best; noise band 230-240us) ----------------
struct DecP {
  const float *dec_start, *sbq, *sbk, *sbv, *sbo, *ln1g, *ln1b,
              *cbq, *cbo, *ln2g, *ln2b, *fb1, *fb2, *ln3g, *ln3b, *ow, *ob;
};

__global__ void __launch_bounds__(256,1) k_dec(const __half* __restrict__ KT,
    const __half* __restrict__ VT, const __half* __restrict__ Wg, DecP P,
    float* __restrict__ out){
  __shared__ __align__(16) __half Wl[29824];       // fp16 weights, 58.25 KB
  __shared__ __align__(16) float peT[kT*kD];       // PE table, 12 KB
  __shared__ __align__(16) __half KhH[kNH*kT*kHD]; // self-K cache fp16, 6 KB
  __shared__ __align__(16) float  Vh[kNH*kT*kHD];  // self-V cache fp32, 12 KB
  __shared__ __align__(16) __half qSH[kNH*kHD];    // q by head, fp16
  __shared__ __align__(16) float poS[kNH][kD];     // per-wave cross-o-proj partials
  __shared__ __align__(16) __half xvH[kD], soH[kD], h1H[kD], cqH[kD], h2H[kD];
  __shared__ __align__(16) __half f1H[kFF];
  int tid=threadIdx.x, b=blockIdx.x, wave=tid>>6, lane=tid&63;
  const float rs=0.28867513459481287f;

  for(int i=tid;i<29824/8;i+=256) ((float4*)Wl)[i]=((const float4*)Wg)[i];
  for(int i=tid;i<kT*kD;i+=256){ int tt=i/kD, j=i%kD; peT[i]=pe_val(tt,j); }

  // wave0 per-lane constants (wave0 runs every stage except cross-attn)
  float c_sbq=0,c_sbk=0,c_sbv=0, c_bo=0,c_cbq=0,c_cbo=0,c_fb2=0;
  float g1=0,bb1=0,g2=0,bb2=0,g3=0,bb3=0,c_ow=0, c_fb1a=0,c_fb1b=0, c_ds=0;
  if(wave==0){
    if(lane<kD){
      c_ds=P.dec_start[lane];
      c_sbq=P.sbq[lane]; c_sbk=P.sbk[lane]; c_sbv=P.sbv[lane];
      c_bo=P.sbo[lane]; c_cbq=P.cbq[lane]; c_cbo=P.cbo[lane]; c_fb2=P.fb2[lane];
      g1=P.ln1g[lane]; bb1=P.ln1b[lane];
      g2=P.ln2g[lane]; bb2=P.ln2b[lane];
      g3=P.ln3g[lane]; bb3=P.ln3b[lane];
      c_ow=P.ow[lane];
    }
    c_fb1a=P.fb1[lane]; c_fb1b=P.fb1[lane+64];
  }
  float c_ob=P.ob[0];

  // cross-attn K/V resident in registers: head = wave, 4 key-PAIRS per lane
  // Kc layout [b][s][d]; Vc layout [b][d][s] read as half2 pairs along s.
  __half2 Kr2[4][2][6], Vr2[4][kHD];   // 48 + 48 VGPRs
  {
    const __half* Kb = KT + (long)b*kS*kD;
    const __half2* Vb = (const __half2*)VT + (long)b*kD*(kS/2);
    #pragma unroll
    for(int i=0;i<4;i++){
      int sp = lane + 64*i;
      #pragma unroll
      for(int e=0;e<2;e++){
        const __half2* kp=(const __half2*)(Kb + (long)(2*sp+e)*kD + wave*kHD);
        #pragma unroll
        for(int c=0;c<6;c++) Kr2[i][e][c]=kp[c];
      }
      #pragma unroll
      for(int u=0;u<kHD;u++) Vr2[i][u]=Vb[(wave*kHD+u)*(kS/2)+sp];
    }
  }
  __syncthreads();

  // peel t=0's A0: wave0 publishes x0
  float xv=0;
  if(wave==0 && lane<kD){ xv=c_ds+peT[lane]; xvH[lane]=__float2half(xv); }
  __syncthreads();

  float h1=0, h2=0, yacc=0;
  for(int t=0;t<kT;t++){
    // ======== A: wave0-only segment (wsync handoffs, no block barriers) ========
    if(wave==0){
      // A1: qkv — x loaded into regs ONCE, reused across 3 dots
      if(lane<kD){
        __half2 xr[24];
        const __half2* xp=(const __half2*)xvH;
        #pragma unroll
        for(int u=0;u<24;u++) xr[u]=xp[u];
        float qv=c_sbq+dot48d(xr, Wl + 0*2688 + lane*56);
        float kv=c_sbk+dot48d(xr, Wl + 1*2688 + lane*56);
        float vv=c_sbv+dot48d(xr, Wl + 2*2688 + lane*56);
        int hh=lane/kHD, dd=lane%kHD;
        qSH[lane]=__float2half(qv);
        KhH[(hh*kT+t)*kHD+dd]=__float2half(kv);
        Vh[(hh*kT+t)*kHD+dd]=vv;
      }
      wsync();
      // A2: self-attn, 4 heads in one wave: lane = head*16 + keygroup
      {
        int hh=lane>>4, g=lane&15;
        __half2 q2[6];
        const __half2* qp=(const __half2*)qSH + hh*6;
        #pragma unroll
        for(int c=0;c<6;c++) q2[c]=qp[c];
        float l=0.f, acc[kHD];
        #pragma unroll
        for(int u=0;u<kHD;u++) acc[u]=0.f;
        #pragma unroll
        for(int kk=0;kk<4;kk++){
          int key=g+16*kk;
          if(key<=t){
            const __half2* kp=(const __half2*)KhH + (hh*kT+key)*6;
            float a0=0.f,a1=0.f;
            a0=fdot2(q2[0],kp[0],a0); a1=fdot2(q2[1],kp[1],a1);
            a0=fdot2(q2[2],kp[2],a0); a1=fdot2(q2[3],kp[3],a1);
            a0=fdot2(q2[4],kp[4],a0); a1=fdot2(q2[5],kp[5],a1);
            float p=__expf((a0+a1)*rs);
            l+=p;
            const float4* vp=(const float4*)(Vh+(hh*kT+key)*kHD);
            float4 v0=vp[0], v1=vp[1], v2=vp[2];
            float vr[kHD]={v0.x,v0.y,v0.z,v0.w,v1.x,v1.y,v1.z,v1.w,v2.x,v2.y,v2.z,v2.w};
            #pragma unroll
            for(int u=0;u<kHD;u++) acc[u]+=p*vr[u];
          }
        }
        l=rowsum16(l);
        #pragma unroll
        for(int u=0;u<kHD;u++) acc[u]=rowsum16(acc[u]);
        if(g==15){
          float inv=1.f/l;
          #pragma unroll
          for(int u=0;u<6;u++)
            ((__half2*)soH)[hh*6+u]=__floats2half2_rn(acc[2*u]*inv, acc[2*u+1]*inv);
        }
      }
      wsync();
      // A3: self o-proj + residual + LN1
      {
        float rr=0.f;
        if(lane<kD)
          rr=xv+c_bo+dot48d((const __half2*)soH, Wl+8064+lane*56);
        float s1=wsum(rr), s2=wsum(rr*rr);
        float mean=s1*(1.f/48.f);
        float rstd=rsqrtf(s2*(1.f/48.f)-mean*mean+1e-5f);
        h1=0;
        if(lane<kD){ h1=(rr-mean)*rstd*g1+bb1; h1H[lane]=__float2half(h1); }
      }
      wsync();
      // A4: cross-q
      if(lane<kD)
        cqH[lane]=__float2half(c_cbq+dot48d((const __half2*)h1H, Wl+10752+lane*56));
    }
    __syncthreads();                                   // B1: cqH -> all waves
    // ======== X: cross-attn on all 4 waves (head = wave); fp32 P, no max-sub;
    //             ends with per-wave PARTIAL cross-o-proj into poS ========
    {
      __half2 q2[6];
      #pragma unroll
      for(int c=0;c<6;c++) q2[c]=((const __half2*)cqH)[wave*6+c];
      float s[8];
      #pragma unroll
      for(int i=0;i<4;i++){
        #pragma unroll
        for(int e=0;e<2;e++){
          float a0=0.f,a1=0.f;
          const __half2* kp=Kr2[i][e];
          a0=fdot2(q2[0],kp[0],a0); a1=fdot2(q2[1],kp[1],a1);
          a0=fdot2(q2[2],kp[2],a0); a1=fdot2(q2[3],kp[3],a1);
          a0=fdot2(q2[4],kp[4],a0); a1=fdot2(q2[5],kp[5],a1);
          s[2*i+e]=(a0+a1)*rs;
        }
      }
      float p32[8], l=0.f;
      #pragma unroll
      for(int j=0;j<8;j++){ p32[j]=__expf(s[j]); l+=p32[j]; }
      l=wsum(l);
      float inv=1.f/l;
      __half2 ph[4];
      #pragma unroll
      for(int i=0;i<4;i++) ph[i]=__floats2half2_rn(p32[2*i]*inv, p32[2*i+1]*inv);
      float acc[kHD];
      #pragma unroll
      for(int u=0;u<kHD;u++) acc[u]=0.f;
      #pragma unroll
      for(int i=0;i<4;i++){
        #pragma unroll
        for(int u=0;u<kHD;u++) acc[u]=fdot2(ph[i],Vr2[i][u],acc[u]);
      }
      #pragma unroll
      for(int u=0;u<kHD;u++) acc[u]=wsum(acc[u]);
      // partial o-proj for this head (moves dot-work BEFORE barrier B2)
      if(lane<kD){
        __half2 ah[6];
        #pragma unroll
        for(int u=0;u<6;u++) ah[u]=__floats2half2_rn(acc[2*u],acc[2*u+1]);
        const __half2* wp=(const __half2*)(Wl+13440+lane*56+wave*kHD);
        float p0=0.f,p1=0.f;
        p0=fdot2(ah[0],wp[0],p0); p1=fdot2(ah[1],wp[1],p1);
        p0=fdot2(ah[2],wp[2],p0); p1=fdot2(ah[3],wp[3],p1);
        p0=fdot2(ah[4],wp[4],p0); p1=fdot2(ah[5],wp[5],p1);
        poS[wave][lane]=p0+p1;
      }
    }
    __syncthreads();                                   // B2: poS -> wave0
    // ======== C: wave0-only segment ========
    if(wave==0){
      // C0: cross o-proj = sum of 4 per-head partials; + residual + LN2
      {
        float rr=0.f;
        if(lane<kD)
          rr=h1+c_cbo+((poS[0][lane]+poS[1][lane])+(poS[2][lane]+poS[3][lane]));
        float s1=wsum(rr), s2=wsum(rr*rr);
        float mean=s1*(1.f/48.f);
        float rstd=rsqrtf(s2*(1.f/48.f)-mean*mean+1e-5f);
        h2=0;
        if(lane<kD){ h2=(rr-mean)*rstd*g2+bb2; h2H[lane]=__float2half(h2); }
      }
      wsync();
      // C1: FFN1 — 2 cols per lane (pipelined)
      {
        float a=c_fb1a+dot48d((const __half2*)h2H, Wl+16128+lane*56);
        float bcol=c_fb1b+dot48d((const __half2*)h2H, Wl+16128+(lane+64)*56);
        f1H[lane]=__float2half(fmaxf(a,0.f));
        f1H[lane+64]=__float2half(fmaxf(bcol,0.f));
      }
      wsync();
      // C2: FFN2 + residual + LN3; fused next-x publish; y into reg buffer
      {
        float rr=0.f;
        if(lane<kD)
          rr=h2+c_fb2+dot128d((const __half2*)f1H, Wl+23296+lane*136);
        float s1=wsum(rr), s2=wsum(rr*rr);
        float mean=s1*(1.f/48.f);
        float rstd=rsqrtf(s2*(1.f/48.f)-mean*mean+1e-5f);
        float cv=0.f;
        if(lane<kD) cv=(rr-mean)*rstd*g3+bb3;
        // publish x_{t+1} FIRST (hides under the y-reduction)
        if(lane<kD && t+1<kT){ xv=cv+peT[(t+1)*kD+lane]; xvH[lane]=__float2half(xv); }
        wsync();
        float y=wsum(cv*c_ow);
        if(lane==t) yacc=y;
      }
    }
  }
  if(wave==0) out[(long)b*kT+lane]=yacc+c_ob;
}

extern "C" void kernel_launch(void* const* d_in, const int* in_sizes, int n_in,
                              void* d_out, int out_size, void* d_ws, size_t ws_size,
                              hipStream_t stream){
  // ws layout: Wh fp16 (64KB) | A fp32 NB | H1/H2/H3 fp16 NB | OP fp16 2*NB | lP fp32 2*BHS
  // total ~46.2 MB
  float* ws = (float*)d_ws;
  __half* Wh = (__half*)ws;
  const size_t NB = (size_t)kB*kS*kD;     // 3,145,728
  const size_t BHS = (size_t)kB*kNH*kS;   // 262,144
  float*  A  = ws + 16384;
  __half* H1 = (__half*)(A + NB);
  __half* H2 = H1 + NB;
  __half* H3 = H2 + NB;
  __half* OP = H3 + NB;
  float*  lP = (float*)(OP + 2*NB);

  // H1=Q (dead after attn -> Kc); H2=K (dead after attn -> LN1-out); H3=V (dead -> Vc)
  k_qkv  <<<2048+102,256,0,stream>>>((const float*)d_in[0],(const float*)d_in[1],(const float*)d_in[2],A,
                                     (const float*)d_in[4],(const float*)d_in[5],(const float*)d_in[6],
                                     (const float*)d_in[7],(const float*)d_in[8],(const float*)d_in[9],H1,H2,H3,
                                     (const float*)d_in[20],(const float*)d_in[22],(const float*)d_in[24],
                                     (const float*)d_in[26],(const float*)d_in[30],(const float*)d_in[36],
                                     (const float*)d_in[40],(const float*)d_in[42],Wh);
  k_attn <<<kB*kNH*2,256,0,stream>>>(H1,H2,H3,OP,lP);
  k_oproj_ln<<<(kB*kS)/32,256,0,stream>>>(A,OP,lP,(const float*)d_in[10],(const float*)d_in[11],
                                          (const float*)d_in[12],(const float*)d_in[13],H2);
  k_ffn_ckv <<<(kB*kS)/16,256,0,stream>>>(H2,(const float*)d_in[14],(const float*)d_in[15],(const float*)d_in[16],
                                          (const float*)d_in[17],(const float*)d_in[18],(const float*)d_in[19],
                                          (const float*)d_in[32],(const float*)d_in[33],
                                          (const float*)d_in[34],(const float*)d_in[35],H1,H3);
  DecP P;
  P.dec_start=(const float*)d_in[3];
  P.sbq=(const float*)d_in[21]; P.sbk=(const float*)d_in[23]; P.sbv=(const float*)d_in[25]; P.sbo=(const float*)d_in[27];
  P.ln1g=(const float*)d_in[28]; P.ln1b=(const float*)d_in[29];
  P.cbq=(const float*)d_in[31]; P.cbo=(const float*)d_in[37];
  P.ln2g=(const float*)d_in[38]; P.ln2b=(const float*)d_in[39];
  P.fb1=(const float*)d_in[41]; P.fb2=(const float*)d_in[43];
  P.ln3g=(const float*)d_in[44]; P.ln3b=(const float*)d_in[45];
  P.ow=(const float*)d_in[46]; P.ob=(const float*)d_in[47];
  k_dec<<<kB,256,0,stream>>>(H1,H3,Wh,P,(float*)d_out);
}